// Round 1
// baseline (336.161 us; speedup 1.0000x reference)
//
#include <hip/hip_runtime.h>

// Problem constants (SCALE=2, K=5, PATCH=3, STRIDE=1)
#define CY     64          // y channels
#define CD     256         // yd channels
#define HY     80          // y spatial
#define HD     40          // yd spatial
#define M1     78          // query patch grid dim  ((80-3)/1+1)
#define N1     38          // matched patch grid dim ((40-3)/1+1)
#define M_TOT  (M1*M1)     // 6084
#define N_TOT  (N1*N1)     // 1444
#define KK     5
#define HS     160         // output spatial
#define EPSF   1e-5f

// Stats of each yd patch: mean and 1/sqrt(var+eps) over 4*3*3=36 elements,
// per (cc in [0,64), n in [0,1444)).  Layout [cc][n].
__global__ void zstats_kernel(const float* __restrict__ yd, float2* __restrict__ zst) {
    int id = blockIdx.x * blockDim.x + threadIdx.x;
    if (id >= CY * N_TOT) return;
    int n  = id % N_TOT;
    int cc = id / N_TOT;
    int ni = n / N1, nj = n - ni * N1;
    const float* base = yd + (cc * 4) * (HD * HD) + ni * HD + nj;
    float s = 0.f, sq = 0.f;
#pragma unroll
    for (int r = 0; r < 4; ++r)
#pragma unroll
        for (int i = 0; i < 3; ++i)
#pragma unroll
            for (int j = 0; j < 3; ++j) {
                float v = base[r * (HD * HD) + i * HD + j];
                s += v; sq += v * v;
            }
    float mu  = s * (1.f / 36.f);
    float var = (sq - 36.f * mu * mu) * (1.f / 35.f);
    zst[id] = make_float2(mu, rsqrtf(var + EPSF));
}

// Stats of each y patch: mean and sqrt(var+eps) over 9 elements,
// per (cc in [0,64), m in [0,6084)).  Layout [cc][m].
__global__ void ystats_kernel(const float* __restrict__ y, float2* __restrict__ yst) {
    int id = blockIdx.x * blockDim.x + threadIdx.x;
    if (id >= CY * M_TOT) return;
    int m  = id % M_TOT;
    int cc = id / M_TOT;
    int mi = m / M1, mj = m - mi * M1;
    const float* base = y + cc * (HY * HY) + mi * HY + mj;
    float s = 0.f, sq = 0.f;
#pragma unroll
    for (int i = 0; i < 3; ++i)
#pragma unroll
        for (int j = 0; j < 3; ++j) {
            float v = base[i * HY + j];
            s += v; sq += v * v;
        }
    float mu  = s * (1.f / 9.f);
    float var = (sq - 9.f * mu * mu) * (1.f / 8.f);
    yst[id] = make_float2(mu, sqrtf(var + EPSF));
}

// Main gather: one thread per output element out[k][cc][Y][X].
// Each output pixel sums <=3x3 patch contributions; the pixel-shuffle phase
// r = (Y&1)*2 + (X&1) is constant per pixel so only one yd channel is read.
__global__ void agg_kernel(const float* __restrict__ yd, const int* __restrict__ idx,
                           const float2* __restrict__ zst, const float2* __restrict__ yst,
                           float* __restrict__ out) {
    int id = blockIdx.x * blockDim.x + threadIdx.x;
    if (id >= KK * CY * HS * HS) return;
    int X = id % HS;
    int t = id / HS;
    int Y = t % HS; t /= HS;
    int cc = t % CY;
    int k  = t / CY;

    int r = ((Y & 1) << 1) | (X & 1);
    const float*  ydc  = yd  + (cc * 4 + r) * (HD * HD);
    const float2* ystc = yst + cc * M_TOT;
    const float2* zstc = zst + cc * N_TOT;

    int mi_lo = max(0, Y - 4) >> 1, mi_hi = min(M1 - 1, Y >> 1);
    int mj_lo = max(0, X - 4) >> 1, mj_hi = min(M1 - 1, X >> 1);

    float sum = 0.f;
    for (int mi = mi_lo; mi <= mi_hi; ++mi) {
        int i = (Y - (mi << 1)) >> 1;       // 0..2
        int rowoff = i * HD;
        for (int mj = mj_lo; mj <= mj_hi; ++mj) {
            int j = (X - (mj << 1)) >> 1;   // 0..2
            int m = mi * M1 + mj;
            int n = idx[m * KK + k];
            float2 ys = ystc[m];
            float2 zs = zstc[n];
            float a = ys.y * zs.y;          // y_sd / z_sd
            float b = ys.x - zs.x * a;      // y_mu - z_mu * a
            int ni = n / N1, nj = n - ni * N1;
            float v = ydc[ni * HD + nj + rowoff + j];
            sum = fmaf(a, v, sum + b);
        }
    }
    float cnt = (float)((mi_hi - mi_lo + 1) * (mj_hi - mj_lo + 1));
    out[id] = sum / cnt;
}

extern "C" void kernel_launch(void* const* d_in, const int* in_sizes, int n_in,
                              void* d_out, int out_size, void* d_ws, size_t ws_size,
                              hipStream_t stream) {
    const float* y   = (const float*)d_in[0];
    const float* yd  = (const float*)d_in[1];
    const int*   idx = (const int*)d_in[2];
    float* out = (float*)d_out;

    char* ws = (char*)d_ws;
    float2* zst = (float2*)ws;                                   // 64*1444*8  = 739,328 B
    float2* yst = (float2*)(ws + (size_t)CY * N_TOT * sizeof(float2)); // 64*6084*8 = 3,115,008 B

    {
        int total = CY * N_TOT;                 // 92,416
        zstats_kernel<<<(total + 255) / 256, 256, 0, stream>>>(yd, zst);
    }
    {
        int total = CY * M_TOT;                 // 389,376
        ystats_kernel<<<(total + 255) / 256, 256, 0, stream>>>(y, yst);
    }
    {
        int total = KK * CY * HS * HS;          // 8,192,000
        agg_kernel<<<(total + 255) / 256, 256, 0, stream>>>(yd, idx, zst, yst, out);
    }
}

// Round 2
// 70.938 us; speedup vs baseline: 4.7388x; 4.7388x over previous
//
#include <hip/hip_runtime.h>

// Problem constants (SCALE=2, K=5, PATCH=3, STRIDE=1)
#define CY     64           // y channels
#define HY     80           // y spatial
#define HD     40           // yd spatial
#define SPD    (HD*HD)      // 1600
#define M1     78           // query patch grid dim
#define N1     38           // matched patch grid dim
#define M_TOT  (M1*M1)      // 6084
#define N_TOT  (N1*N1)      // 1444
#define KK     5
#define HS     160          // output spatial
#define EPSF   1e-5f

// yd [256][1600]  ->  ydT [4][1600][64]   (r, spatial, cc)
__global__ void transpose_yd(const float* __restrict__ yd, float* __restrict__ ydT) {
    int id = blockIdx.x * blockDim.x + threadIdx.x;
    if (id >= 256 * SPD) return;
    int sp = id % SPD;
    int c  = id / SPD;           // c = cc*4 + r
    int cc = c >> 2, r = c & 3;
    ydT[(r * SPD + sp) * 64 + cc] = yd[id];
}

// Per-(n,cc) stats of yd patches: mean, 1/sqrt(var+eps) over 36 elems. Layout [n][cc].
__global__ void zstatsT_kernel(const float* __restrict__ yd, float2* __restrict__ zstT) {
    int id = blockIdx.x * blockDim.x + threadIdx.x;
    if (id >= CY * N_TOT) return;
    int n  = id % N_TOT;         // lanes = consecutive n -> coalesced reads
    int cc = id / N_TOT;
    int ni = n / N1, nj = n - ni * N1;
    const float* base = yd + (cc * 4) * SPD + ni * HD + nj;
    float s = 0.f, sq = 0.f;
#pragma unroll
    for (int r = 0; r < 4; ++r)
#pragma unroll
        for (int i = 0; i < 3; ++i)
#pragma unroll
            for (int j = 0; j < 3; ++j) {
                float v = base[r * SPD + i * HD + j];
                s += v; sq += v * v;
            }
    float mu  = s * (1.f / 36.f);
    float var = (sq - 36.f * mu * mu) * (1.f / 35.f);
    zstT[n * 64 + cc] = make_float2(mu, rsqrtf(var + EPSF));
}

// Per-(m,cc) stats of y patches: mean, sqrt(var+eps) over 9 elems. Layout [m][cc].
__global__ void ystatsT_kernel(const float* __restrict__ y, float2* __restrict__ ystT) {
    int id = blockIdx.x * blockDim.x + threadIdx.x;
    if (id >= CY * M_TOT) return;
    int m  = id % M_TOT;         // lanes = consecutive m -> coalesced reads
    int cc = id / M_TOT;
    int mi = m / M1, mj = m - mi * M1;
    const float* base = y + cc * (HY * HY) + mi * HY + mj;
    float s = 0.f, sq = 0.f;
#pragma unroll
    for (int i = 0; i < 3; ++i)
#pragma unroll
        for (int j = 0; j < 3; ++j) {
            float v = base[i * HY + j];
            s += v; sq += v * v;
        }
    float mu  = s * (1.f / 9.f);
    float var = (sq - 9.f * mu * mu) * (1.f / 8.f);
    ystT[m * 64 + cc] = make_float2(mu, sqrtf(var + EPSF));
}

// Main: one WAVE per output 2x2 quad (x,y), lanes = 64 channels, k-loop inside.
// All 4 quad pixels share the same 3x3 patch set; i=y-mi, j=x-mj are quad-uniform;
// only the pixel-shuffle phase r=dy*2+dx differs -> 4 ydT reads per (patch,k).
__global__ __launch_bounds__(256) void agg_kernel(
    const int* __restrict__ idx, const float* __restrict__ ydT,
    const float2* __restrict__ zstT, const float2* __restrict__ ystT,
    float* __restrict__ out)
{
    int lane = threadIdx.x & 63;
    int wave = __builtin_amdgcn_readfirstlane(threadIdx.x >> 6);
    int bid  = blockIdx.x;            // 0..1599
    int y = bid / 20;                 // quad row 0..79
    int x = (bid % 20) * 4 + wave;    // quad col 0..79

    int mi_lo = max(0, y - 2), mi_hi = min(M1 - 1, y);
    int mj_lo = max(0, x - 2), mj_hi = min(M1 - 1, x);

    float acc[KK][4];
#pragma unroll
    for (int k = 0; k < KK; ++k)
#pragma unroll
        for (int r = 0; r < 4; ++r) acc[k][r] = 0.f;

    auto do_patch = [&](int mi, int mj) {
        int i = y - mi, j = x - mj;           // 0..2, wave-uniform
        int m = mi * M1 + mj;
        float2 ys = ystT[m * 64 + lane];
        const int* ip = idx + m * KK;
#pragma unroll
        for (int k = 0; k < KK; ++k) {
            int n = __builtin_amdgcn_readfirstlane(ip[k]);   // wave-uniform
            float2 zs = zstT[n * 64 + lane];
            float a = ys.y * zs.y;                            // y_sd * inv_z_sd
            float b = fmaf(-zs.x, a, ys.x);                   // y_mu - z_mu*a
            int ni = n / N1, nj = n - ni * N1;
            int sp = (ni + i) * HD + nj + j;
            const float* base = ydT + sp * 64 + lane;
#pragma unroll
            for (int r = 0; r < 4; ++r)
                acc[k][r] = fmaf(a, base[r * SPD * 64], acc[k][r] + b);
        }
    };

    if (((mi_hi - mi_lo) == 2) && ((mj_hi - mj_lo) == 2)) {
#pragma unroll
        for (int di = 0; di < 3; ++di)
#pragma unroll
            for (int dj = 0; dj < 3; ++dj)
                do_patch(mi_lo + di, mj_lo + dj);
    } else {
        for (int mi = mi_lo; mi <= mi_hi; ++mi)
            for (int mj = mj_lo; mj <= mj_hi; ++mj)
                do_patch(mi, mj);
    }

    float inv = 1.f / (float)((mi_hi - mi_lo + 1) * (mj_hi - mj_lo + 1));
    int Y = 2 * y, X = 2 * x;
#pragma unroll
    for (int k = 0; k < KK; ++k) {
#pragma unroll
        for (int dy = 0; dy < 2; ++dy) {
            float2 v = make_float2(acc[k][dy * 2] * inv, acc[k][dy * 2 + 1] * inv);
            *(float2*)(out + (((size_t)(k * CY + lane) * HS + (Y + dy)) * HS + X)) = v;
        }
    }
}

extern "C" void kernel_launch(void* const* d_in, const int* in_sizes, int n_in,
                              void* d_out, int out_size, void* d_ws, size_t ws_size,
                              hipStream_t stream) {
    const float* y   = (const float*)d_in[0];
    const float* yd  = (const float*)d_in[1];
    const int*   idx = (const int*)d_in[2];
    float* out = (float*)d_out;

    char* ws = (char*)d_ws;
    float*  ydT  = (float*)ws;                                  // 4*1600*64*4   = 1,638,400 B
    float2* zstT = (float2*)(ws + 1638400);                     // 1444*64*8     =   739,328 B
    float2* ystT = (float2*)(ws + 1638400 + 739328);            // 6084*64*8     = 3,115,008 B

    transpose_yd<<<(256 * SPD + 255) / 256, 256, 0, stream>>>(yd, ydT);
    zstatsT_kernel<<<(CY * N_TOT + 255) / 256, 256, 0, stream>>>(yd, zstT);
    ystatsT_kernel<<<(CY * M_TOT + 255) / 256, 256, 0, stream>>>(y, ystT);
    agg_kernel<<<1600, 256, 0, stream>>>(idx, ydT, zstT, ystT, out);
}

// Round 3
// 67.131 us; speedup vs baseline: 5.0076x; 1.0567x over previous
//
#include <hip/hip_runtime.h>

// Problem constants (SCALE=2, K=5, PATCH=3, STRIDE=1)
#define CY     64           // y channels
#define HY     80           // y spatial
#define HD     40           // yd spatial
#define SPD    (HD*HD)      // 1600
#define M1     78           // query patch grid dim
#define N1     38           // matched patch grid dim
#define M_TOT  (M1*M1)      // 6084
#define N_TOT  (N1*N1)      // 1444
#define KK     5
#define HS     160          // output spatial
#define EPSF   1e-5f

// yd [256][1600] -> ydT4 [sp][cc] = float4 over r   (so one lane-load gets all 4 phases)
__global__ __launch_bounds__(256) void transpose_yd(const float* __restrict__ yd,
                                                    float4* __restrict__ ydT4) {
    int id = blockIdx.x * blockDim.x + threadIdx.x;
    if (id >= SPD * 64) return;
    int cc = id & 63, sp = id >> 6;          // lanes = cc -> coalesced float4 writes
    float4 v;
    v.x = yd[(cc * 4 + 0) * SPD + sp];
    v.y = yd[(cc * 4 + 1) * SPD + sp];
    v.z = yd[(cc * 4 + 2) * SPD + sp];
    v.w = yd[(cc * 4 + 3) * SPD + sp];
    ydT4[sp * 64 + cc] = v;
}

// Fused stats. First 361 blocks: zstT[n][cc] = (mu, 1/sd) over 36 elems (reads ydT4 coalesced).
// Remaining blocks: ystT[m][cc] = (mu, sd) over 9 elems.
__global__ __launch_bounds__(256) void stats_kernel(const float* __restrict__ y,
                                                    const float4* __restrict__ ydT4,
                                                    float2* __restrict__ zstT,
                                                    float2* __restrict__ ystT) {
    int id = blockIdx.x * blockDim.x + threadIdx.x;
    if (id < N_TOT * 64) {
        int cc = id & 63, n = id >> 6;       // lanes = cc -> coalesced
        int ni = n / N1, nj = n - ni * N1;
        float s = 0.f, sq = 0.f;
#pragma unroll
        for (int i = 0; i < 3; ++i)
#pragma unroll
            for (int j = 0; j < 3; ++j) {
                float4 v = ydT4[((ni + i) * HD + nj + j) * 64 + cc];
                s  += v.x + v.y + v.z + v.w;
                sq += v.x * v.x + v.y * v.y + v.z * v.z + v.w * v.w;
            }
        float mu  = s * (1.f / 36.f);
        float var = (sq - 36.f * mu * mu) * (1.f / 35.f);
        zstT[n * 64 + cc] = make_float2(mu, rsqrtf(var + EPSF));
        return;
    }
    int id2 = id - N_TOT * 64;
    if (id2 >= CY * M_TOT) return;
    int m  = id2 % M_TOT;                    // lanes = consecutive m -> coalesced reads
    int cc = id2 / M_TOT;
    int mi = m / M1, mj = m - mi * M1;
    const float* base = y + cc * (HY * HY) + mi * HY + mj;
    float s = 0.f, sq = 0.f;
#pragma unroll
    for (int i = 0; i < 3; ++i)
#pragma unroll
        for (int j = 0; j < 3; ++j) {
            float v = base[i * HY + j];
            s += v; sq += v * v;
        }
    float mu  = s * (1.f / 9.f);
    float var = (sq - 9.f * mu * mu) * (1.f / 8.f);
    ystT[m * 64 + cc] = make_float2(mu, sqrtf(var + EPSF));
}

// Main: 512-thread block = 8 waves = 8 x-quads (16 X pixels = one 64B span per (k,cc,Y) row).
// Wave = one 2x2 output quad, lanes = 64 channels, k-loop inside.
__global__ __launch_bounds__(512) void agg_kernel(
    const int* __restrict__ idx, const float4* __restrict__ ydT4,
    const float2* __restrict__ zstT, const float2* __restrict__ ystT,
    float* __restrict__ out)
{
    int lane = threadIdx.x & 63;
    int wave = __builtin_amdgcn_readfirstlane(threadIdx.x >> 6);  // 0..7
    int bid  = blockIdx.x;            // 0..799
    int y = bid / 10;                 // quad row 0..79
    int x = (bid % 10) * 8 + wave;    // quad col 0..79

    int mi_lo = max(0, y - 2), mi_hi = min(M1 - 1, y);
    int mj_lo = max(0, x - 2), mj_hi = min(M1 - 1, x);

    float acc[KK][4];
#pragma unroll
    for (int k = 0; k < KK; ++k)
#pragma unroll
        for (int r = 0; r < 4; ++r) acc[k][r] = 0.f;

    auto do_patch = [&](int mi, int mj) {
        int i = y - mi, j = x - mj;           // 0..2, wave-uniform
        int m = mi * M1 + mj;
        float2 ys = ystT[m * 64 + lane];
        const int* ip = idx + m * KK;
#pragma unroll
        for (int k = 0; k < KK; ++k) {
            int n = __builtin_amdgcn_readfirstlane(ip[k]);   // wave-uniform
            float2 zs = zstT[n * 64 + lane];
            float a = ys.y * zs.y;                            // y_sd * inv_z_sd
            float b = fmaf(-zs.x, a, ys.x);                   // y_mu - z_mu*a
            int ni = n / N1, nj = n - ni * N1;
            int sp = (ni + i) * HD + nj + j;
            float4 v = ydT4[sp * 64 + lane];                  // all 4 phases in one load
            const float* vf = (const float*)&v;
#pragma unroll
            for (int r = 0; r < 4; ++r)
                acc[k][r] = fmaf(a, vf[r], acc[k][r] + b);
        }
    };

    if (((mi_hi - mi_lo) == 2) && ((mj_hi - mj_lo) == 2)) {
#pragma unroll
        for (int di = 0; di < 3; ++di)
#pragma unroll
            for (int dj = 0; dj < 3; ++dj)
                do_patch(mi_lo + di, mj_lo + dj);
    } else {
        for (int mi = mi_lo; mi <= mi_hi; ++mi)
            for (int mj = mj_lo; mj <= mj_hi; ++mj)
                do_patch(mi, mj);
    }

    float inv = 1.f / (float)((mi_hi - mi_lo + 1) * (mj_hi - mj_lo + 1));
    int Y = 2 * y, X = 2 * x;
#pragma unroll
    for (int k = 0; k < KK; ++k) {
#pragma unroll
        for (int dy = 0; dy < 2; ++dy) {
            float2 v = make_float2(acc[k][dy * 2] * inv, acc[k][dy * 2 + 1] * inv);
            *(float2*)(out + (((size_t)(k * CY + lane) * HS + (Y + dy)) * HS + X)) = v;
        }
    }
}

extern "C" void kernel_launch(void* const* d_in, const int* in_sizes, int n_in,
                              void* d_out, int out_size, void* d_ws, size_t ws_size,
                              hipStream_t stream) {
    const float* y   = (const float*)d_in[0];
    const float* yd  = (const float*)d_in[1];
    const int*   idx = (const int*)d_in[2];
    float* out = (float*)d_out;

    char* ws = (char*)d_ws;
    float4* ydT4 = (float4*)ws;                                 // 1600*64*16 = 1,638,400 B
    float2* zstT = (float2*)(ws + 1638400);                     // 1444*64*8  =   739,328 B
    float2* ystT = (float2*)(ws + 1638400 + 739328);            // 6084*64*8  = 3,115,008 B

    transpose_yd<<<(SPD * 64 + 255) / 256, 256, 0, stream>>>(yd, ydT4);
    stats_kernel<<<(N_TOT * 64 + CY * M_TOT + 255) / 256, 256, 0, stream>>>(y, ydT4, zstT, ystT);
    agg_kernel<<<800, 512, 0, stream>>>(idx, ydT4, zstT, ystT, out);
}

// Round 4
// 46.119 us; speedup vs baseline: 7.2889x; 1.4556x over previous
//
#include <hip/hip_runtime.h>

// Problem constants (SCALE=2, K=5, PATCH=3, STRIDE=1)
#define CY     64           // y channels
#define HY     80           // y spatial
#define HD     40           // yd spatial
#define SPD    (HD*HD)      // 1600
#define M1     78           // query patch grid dim
#define N1     38           // matched patch grid dim
#define M_TOT  (M1*M1)      // 6084
#define N_TOT  (N1*N1)      // 1444
#define KK     5
#define HS     160          // output spatial
#define EPSF   1e-5f
#define LPITCH 17           // LDS row pitch (floats): write stride 17 (2-way), read groups +16 rows -> 2-way

// yd [256][1600] -> ydT4 [sp][cc] = float4 over r   (one lane-load gets all 4 shuffle phases)
__global__ __launch_bounds__(256) void transpose_yd(const float* __restrict__ yd,
                                                    float4* __restrict__ ydT4) {
    int id = blockIdx.x * blockDim.x + threadIdx.x;
    if (id >= SPD * 64) return;
    int cc = id & 63, sp = id >> 6;          // lanes = cc -> coalesced float4 writes
    float4 v;
    v.x = yd[(cc * 4 + 0) * SPD + sp];
    v.y = yd[(cc * 4 + 1) * SPD + sp];
    v.z = yd[(cc * 4 + 2) * SPD + sp];
    v.w = yd[(cc * 4 + 3) * SPD + sp];
    ydT4[sp * 64 + cc] = v;
}

// Fused stats. First 361*256 threads: zstT[n][cc] = (mu, 1/sd) over 36 elems (reads ydT4 coalesced).
// Rest: ystT[m][cc] = (mu, sd) over 9 elems.
__global__ __launch_bounds__(256) void stats_kernel(const float* __restrict__ y,
                                                    const float4* __restrict__ ydT4,
                                                    float2* __restrict__ zstT,
                                                    float2* __restrict__ ystT) {
    int id = blockIdx.x * blockDim.x + threadIdx.x;
    if (id < N_TOT * 64) {
        int cc = id & 63, n = id >> 6;       // lanes = cc -> coalesced
        int ni = n / N1, nj = n - ni * N1;
        float s = 0.f, sq = 0.f;
#pragma unroll
        for (int i = 0; i < 3; ++i)
#pragma unroll
            for (int j = 0; j < 3; ++j) {
                float4 v = ydT4[((ni + i) * HD + nj + j) * 64 + cc];
                s  += v.x + v.y + v.z + v.w;
                sq += v.x * v.x + v.y * v.y + v.z * v.z + v.w * v.w;
            }
        float mu  = s * (1.f / 36.f);
        float var = (sq - 36.f * mu * mu) * (1.f / 35.f);
        zstT[n * 64 + cc] = make_float2(mu, rsqrtf(var + EPSF));
        return;
    }
    int id2 = id - N_TOT * 64;
    if (id2 >= CY * M_TOT) return;
    int m  = id2 % M_TOT;                    // lanes = consecutive m -> coalesced reads
    int cc = id2 / M_TOT;
    int mi = m / M1, mj = m - mi * M1;
    const float* base = y + cc * (HY * HY) + mi * HY + mj;
    float s = 0.f, sq = 0.f;
#pragma unroll
    for (int i = 0; i < 3; ++i)
#pragma unroll
        for (int j = 0; j < 3; ++j) {
            float v = base[i * HY + j];
            s += v; sq += v * v;
        }
    float mu  = s * (1.f / 9.f);
    float var = (sq - 9.f * mu * mu) * (1.f / 8.f);
    ystT[m * 64 + cc] = make_float2(mu, sqrtf(var + EPSF));
}

// Main: block = 8 waves = 8 x-quads (16 X pixels) at one quad-row y.
// Compute: wave = one 2x2 quad, lanes = cc, k-loop inside (all reads coalesced/scalar).
// Epilogue: LDS transpose so every global store instruction writes 4 FULL 64B lines.
__global__ __launch_bounds__(512) void agg_kernel(
    const int* __restrict__ idx, const float4* __restrict__ ydT4,
    const float2* __restrict__ zstT, const float2* __restrict__ ystT,
    float* __restrict__ out)
{
    __shared__ float lds[KK * 2 * CY * LPITCH];   // 10880 floats = 43,520 B

    int lane = threadIdx.x & 63;
    int wave = __builtin_amdgcn_readfirstlane(threadIdx.x >> 6);  // 0..7
    int bid  = blockIdx.x;            // 0..799
    int y  = bid / 10;                // quad row 0..79
    int xb = bid % 10;                // x block 0..9
    int x  = xb * 8 + wave;           // quad col 0..79

    int mi_lo = max(0, y - 2), mi_hi = min(M1 - 1, y);
    int mj_lo = max(0, x - 2), mj_hi = min(M1 - 1, x);

    float acc[KK][4];
#pragma unroll
    for (int k = 0; k < KK; ++k)
#pragma unroll
        for (int r = 0; r < 4; ++r) acc[k][r] = 0.f;

    auto do_patch = [&](int mi, int mj) {
        int i = y - mi, j = x - mj;           // 0..2, wave-uniform
        int m = mi * M1 + mj;
        float2 ys = ystT[m * 64 + lane];
        const int* ip = idx + m * KK;
#pragma unroll
        for (int k = 0; k < KK; ++k) {
            int n = __builtin_amdgcn_readfirstlane(ip[k]);   // wave-uniform
            float2 zs = zstT[n * 64 + lane];
            float a = ys.y * zs.y;                            // y_sd * inv_z_sd
            float b = fmaf(-zs.x, a, ys.x);                   // y_mu - z_mu*a
            int ni = n / N1, nj = n - ni * N1;
            int sp = (ni + i) * HD + nj + j;
            float4 v = ydT4[sp * 64 + lane];                  // all 4 phases in one load
            const float* vf = (const float*)&v;
#pragma unroll
            for (int r = 0; r < 4; ++r)
                acc[k][r] = fmaf(a, vf[r], acc[k][r] + b);
        }
    };

    if (((mi_hi - mi_lo) == 2) && ((mj_hi - mj_lo) == 2)) {
#pragma unroll
        for (int di = 0; di < 3; ++di)
#pragma unroll
            for (int dj = 0; dj < 3; ++dj)
                do_patch(mi_lo + di, mj_lo + dj);
    } else {
        for (int mi = mi_lo; mi <= mi_hi; ++mi)
            for (int mj = mj_lo; mj <= mj_hi; ++mj)
                do_patch(mi, mj);
    }

    float inv = 1.f / (float)((mi_hi - mi_lo + 1) * (mj_hi - mj_lo + 1));

    // Stage (normalized) results: row = (k*2+dy)*64 + cc, col = wave*2 + dx.
    // Lanes (cc) stride LPITCH=17 -> all 32 banks hit by cc&31 -> free 2-way.
#pragma unroll
    for (int k = 0; k < KK; ++k)
#pragma unroll
        for (int dy = 0; dy < 2; ++dy) {
            int base = ((k * 2 + dy) * CY + lane) * LPITCH + wave * 2;
            lds[base]     = acc[k][dy * 2]     * inv;
            lds[base + 1] = acc[k][dy * 2 + 1] * inv;
        }

    __syncthreads();

    // Drain: 20 items/wave; each wave-load covers rows {cc0, cc0+16, cc0+32, cc0+48}
    // (17*16 = 272 = 16 mod 32 -> exact free 2-way), each 16-lane group writes one FULL 64B line.
    int q  = lane >> 4;               // 0..3
    int xi = lane & 15;               // 0..15
    int X0 = xb * 16;
    int Y0 = 2 * y;
#pragma unroll
    for (int t = 0; t < 20; ++t) {
        int item = wave + t * 8;      // 0..159
        int c0 = item & 15;
        int kd = item >> 4;           // k*2+dy, 0..9
        int cc = c0 + (q << 4);
        float v = lds[(kd * CY + cc) * LPITCH + xi];
        int k  = kd >> 1, dy = kd & 1;
        out[((size_t)(k * CY + cc) * HS + (Y0 + dy)) * HS + X0 + xi] = v;
    }
}

extern "C" void kernel_launch(void* const* d_in, const int* in_sizes, int n_in,
                              void* d_out, int out_size, void* d_ws, size_t ws_size,
                              hipStream_t stream) {
    const float* y   = (const float*)d_in[0];
    const float* yd  = (const float*)d_in[1];
    const int*   idx = (const int*)d_in[2];
    float* out = (float*)d_out;

    char* ws = (char*)d_ws;
    float4* ydT4 = (float4*)ws;                                 // 1600*64*16 = 1,638,400 B
    float2* zstT = (float2*)(ws + 1638400);                     // 1444*64*8  =   739,328 B
    float2* ystT = (float2*)(ws + 1638400 + 739328);            // 6084*64*8  = 3,115,008 B

    transpose_yd<<<(SPD * 64 + 255) / 256, 256, 0, stream>>>(yd, ydT4);
    stats_kernel<<<(N_TOT * 64 + CY * M_TOT + 255) / 256, 256, 0, stream>>>(y, ydT4, zstT, ystT);
    agg_kernel<<<800, 512, 0, stream>>>(idx, ydT4, zstT, ystT, out);
}

// Round 5
// 44.999 us; speedup vs baseline: 7.4704x; 1.0249x over previous
//
#include <hip/hip_runtime.h>

// Problem constants (SCALE=2, K=5, PATCH=3, STRIDE=1)
#define CY     64           // y channels
#define HY     80           // y spatial
#define HD     40           // yd spatial
#define SPD    (HD*HD)      // 1600
#define M1     78           // query patch grid dim
#define N1     38           // matched patch grid dim
#define M_TOT  (M1*M1)      // 6084
#define N_TOT  (N1*N1)      // 1444
#define KK     5
#define HS     160          // output spatial
#define EPSF   1e-5f
#define LPITCH 17           // LDS row pitch (floats) -> 2-way max on both phases (free)

// Fused pre-pass, partitioned by flat thread id:
//  A: yd [256][1600] -> ydT4[sp][cc] = float4 over r (pixel-shuffle phases)
//  B: zstT[n][cc] = (mu, 1/sd) over 36 elems, read from raw yd (lanes = consecutive n)
//  C: ystT[m][cc] = (mu, sd) over 9 elems, read from y (lanes = consecutive m)
__global__ __launch_bounds__(256) void pre_kernel(const float* __restrict__ y,
                                                  const float* __restrict__ yd,
                                                  float4* __restrict__ ydT4,
                                                  float2* __restrict__ zstT,
                                                  float2* __restrict__ ystT) {
    int id = blockIdx.x * 256 + threadIdx.x;
    if (id < SPD * 64) {                       // ---- A: transpose
        int cc = id & 63, sp = id >> 6;
        float4 v;
        v.x = yd[(cc * 4 + 0) * SPD + sp];
        v.y = yd[(cc * 4 + 1) * SPD + sp];
        v.z = yd[(cc * 4 + 2) * SPD + sp];
        v.w = yd[(cc * 4 + 3) * SPD + sp];
        ydT4[sp * 64 + cc] = v;
        return;
    }
    id -= SPD * 64;
    if (id < N_TOT * 64) {                     // ---- B: z-stats
        int n  = id % N_TOT;                   // lanes = consecutive n -> coalesced reads
        int cc = id / N_TOT;
        int ni = n / N1, nj = n - ni * N1;
        const float* base = yd + (cc * 4) * SPD + ni * HD + nj;
        float s = 0.f, sq = 0.f;
#pragma unroll
        for (int r = 0; r < 4; ++r)
#pragma unroll
            for (int i = 0; i < 3; ++i)
#pragma unroll
                for (int j = 0; j < 3; ++j) {
                    float v = base[r * SPD + i * HD + j];
                    s += v; sq += v * v;
                }
        float mu  = s * (1.f / 36.f);
        float var = (sq - 36.f * mu * mu) * (1.f / 35.f);
        zstT[n * 64 + cc] = make_float2(mu, rsqrtf(var + EPSF));
        return;
    }
    id -= N_TOT * 64;
    if (id >= CY * M_TOT) return;              // ---- C: y-stats
    int m  = id % M_TOT;                       // lanes = consecutive m -> coalesced reads
    int cc = id / M_TOT;
    int mi = m / M1, mj = m - mi * M1;
    const float* base = y + cc * (HY * HY) + mi * HY + mj;
    float s = 0.f, sq = 0.f;
#pragma unroll
    for (int i = 0; i < 3; ++i)
#pragma unroll
        for (int j = 0; j < 3; ++j) {
            float v = base[i * HY + j];
            s += v; sq += v * v;
        }
    float mu  = s * (1.f / 9.f);
    float var = (sq - 9.f * mu * mu) * (1.f / 8.f);
    ystT[m * 64 + cc] = make_float2(mu, sqrtf(var + EPSF));
}

// Main: block = 8 waves = 8 x-quads at one (quad-row y, k). Wave = (2x2 quad, one k),
// lanes = cc. Prefetch all 9 n + 9 ystT up front -> 18 independent dependent-depth-1 loads.
// Epilogue: LDS transpose so every global store instruction writes 4 FULL 64B lines.
__global__ __launch_bounds__(512) void agg_kernel(
    const int* __restrict__ idx, const float4* __restrict__ ydT4,
    const float2* __restrict__ zstT, const float2* __restrict__ ystT,
    float* __restrict__ out)
{
    __shared__ float lds[2 * CY * LPITCH];     // 2176 floats = 8704 B

    int lane = threadIdx.x & 63;
    int wave = __builtin_amdgcn_readfirstlane(threadIdx.x >> 6);  // 0..7
    int bid  = blockIdx.x;            // k*800 + y*10 + xb
    int k   = bid / 800;
    int rem = bid - k * 800;
    int y   = rem / 10;               // quad row 0..79
    int xb  = rem - y * 10;           // x block 0..9
    int x   = xb * 8 + wave;          // quad col 0..79

    int mi_lo = max(0, y - 2), mi_hi = min(M1 - 1, y);
    int mj_lo = max(0, x - 2), mj_hi = min(M1 - 1, x);

    float acc[4] = {0.f, 0.f, 0.f, 0.f};
    int cnt;

    if (((mi_hi - mi_lo) == 2) && ((mj_hi - mj_lo) == 2)) {
        cnt = 9;
        int   n_[9];
        float2 ys_[9];
#pragma unroll
        for (int p = 0; p < 9; ++p) {          // all loads independent, issued up front
            int mi = mi_lo + p / 3, mj = mj_lo + p % 3;
            int m  = mi * M1 + mj;
            n_[p]  = idx[m * KK + k];
            ys_[p] = ystT[m * 64 + lane];
        }
#pragma unroll
        for (int p = 0; p < 9; ++p) {
            int n = __builtin_amdgcn_readfirstlane(n_[p]);
            float2 zs = zstT[n * 64 + lane];
            int ni = n / N1, nj = n - ni * N1;
            int i = 2 - p / 3, j = 2 - p % 3;  // y-mi, x-mj for interior
            float4 v = ydT4[((ni + i) * HD + nj + j) * 64 + lane];
            float a = ys_[p].y * zs.y;
            float b = fmaf(-zs.x, a, ys_[p].x);
            const float* vf = (const float*)&v;
#pragma unroll
            for (int r = 0; r < 4; ++r)
                acc[r] = fmaf(a, vf[r], acc[r] + b);
        }
    } else {
        cnt = (mi_hi - mi_lo + 1) * (mj_hi - mj_lo + 1);
        for (int mi = mi_lo; mi <= mi_hi; ++mi)
            for (int mj = mj_lo; mj <= mj_hi; ++mj) {
                int m = mi * M1 + mj;
                int n = __builtin_amdgcn_readfirstlane(idx[m * KK + k]);
                float2 ys = ystT[m * 64 + lane];
                float2 zs = zstT[n * 64 + lane];
                float a = ys.y * zs.y;
                float b = fmaf(-zs.x, a, ys.x);
                int ni = n / N1, nj = n - ni * N1;
                int i = y - mi, j = x - mj;
                float4 v = ydT4[((ni + i) * HD + nj + j) * 64 + lane];
                const float* vf = (const float*)&v;
#pragma unroll
                for (int r = 0; r < 4; ++r)
                    acc[r] = fmaf(a, vf[r], acc[r] + b);
            }
    }

    float inv = 1.f / (float)cnt;

    // Stage: row = dy*64 + cc, col = wave*2 + dx. Lane stride 17 -> free 2-way.
#pragma unroll
    for (int dy = 0; dy < 2; ++dy) {
        int base = (dy * CY + lane) * LPITCH + wave * 2;
        lds[base]     = acc[dy * 2]     * inv;
        lds[base + 1] = acc[dy * 2 + 1] * inv;
    }

    __syncthreads();

    // Drain: 128 rows x 16 cols; each 16-lane group writes one FULL 64B line.
    int q  = lane >> 4;               // 0..3
    int xi = lane & 15;               // 0..15
    int X0 = xb * 16;
    int Y0 = 2 * y;
#pragma unroll
    for (int t = 0; t < 4; ++t) {
        int row = t * 32 + wave * 4 + q;       // 0..127
        int dy = row >> 6, cc = row & 63;
        float v = lds[row * LPITCH + xi];
        out[((size_t)(k * CY + cc) * HS + (Y0 + dy)) * HS + X0 + xi] = v;
    }
}

extern "C" void kernel_launch(void* const* d_in, const int* in_sizes, int n_in,
                              void* d_out, int out_size, void* d_ws, size_t ws_size,
                              hipStream_t stream) {
    const float* y   = (const float*)d_in[0];
    const float* yd  = (const float*)d_in[1];
    const int*   idx = (const int*)d_in[2];
    float* out = (float*)d_out;

    char* ws = (char*)d_ws;
    float4* ydT4 = (float4*)ws;                                 // 1600*64*16 = 1,638,400 B
    float2* zstT = (float2*)(ws + 1638400);                     // 1444*64*8  =   739,328 B
    float2* ystT = (float2*)(ws + 1638400 + 739328);            // 6084*64*8  = 3,115,008 B

    int pre_total = SPD * 64 + N_TOT * 64 + CY * M_TOT;         // 584,192
    pre_kernel<<<(pre_total + 255) / 256, 256, 0, stream>>>(y, yd, ydT4, zstT, ystT);
    agg_kernel<<<KK * 800, 512, 0, stream>>>(idx, ydT4, zstT, ystT, out);
}

// Round 6
// 42.633 us; speedup vs baseline: 7.8850x; 1.0555x over previous
//
#include <hip/hip_runtime.h>

// Problem constants (SCALE=2, K=5, PATCH=3, STRIDE=1)
#define CY     64           // y channels
#define HY     80           // y spatial
#define HD     40           // yd spatial
#define SPD    (HD*HD)      // 1600
#define M1     78           // query patch grid dim
#define N1     38           // matched patch grid dim
#define M_TOT  (M1*M1)      // 6084
#define N_TOT  (N1*N1)      // 1444
#define KK     5
#define HS     160          // output spatial
#define EPSF   1e-5f
#define LPITCH 17           // LDS row pitch (floats) -> free 2-way on both phases

// round-to-nearest-even f32->bf16, packed pair (a in low 16, b in high 16)
__device__ __forceinline__ unsigned bf16pk(float a, float b) {
    unsigned ua = __float_as_uint(a), ub = __float_as_uint(b);
    ua = (ua + 0x7fffu + ((ua >> 16) & 1u)) >> 16;
    ub = (ub + 0x7fffu + ((ub >> 16) & 1u)) >> 16;
    return ua | (ub << 16);
}

// Fused pre-pass, partitioned by flat thread id:
//  A: yd [256][1600] -> ydT4h[sp][cc] = 4 x bf16 over r (pixel-shuffle phases), 8B/lane
//  B: zstT[n][cc] = (mu, 1/sd) over 36 elems (f32)
//  C: ystT[m][cc] = (mu, sd) over 9 elems (f32)
__global__ __launch_bounds__(256) void pre_kernel(const float* __restrict__ y,
                                                  const float* __restrict__ yd,
                                                  uint2* __restrict__ ydT4h,
                                                  float2* __restrict__ zstT,
                                                  float2* __restrict__ ystT) {
    int id = blockIdx.x * 256 + threadIdx.x;
    if (id < SPD * 64) {                       // ---- A: transpose + bf16 pack
        int cc = id & 63, sp = id >> 6;
        float v0 = yd[(cc * 4 + 0) * SPD + sp];
        float v1 = yd[(cc * 4 + 1) * SPD + sp];
        float v2 = yd[(cc * 4 + 2) * SPD + sp];
        float v3 = yd[(cc * 4 + 3) * SPD + sp];
        ydT4h[sp * 64 + cc] = make_uint2(bf16pk(v0, v1), bf16pk(v2, v3));
        return;
    }
    id -= SPD * 64;
    if (id < N_TOT * 64) {                     // ---- B: z-stats
        int n  = id % N_TOT;                   // lanes = consecutive n -> coalesced
        int cc = id / N_TOT;
        int ni = n / N1, nj = n - ni * N1;
        const float* base = yd + (cc * 4) * SPD + ni * HD + nj;
        float s = 0.f, sq = 0.f;
#pragma unroll
        for (int r = 0; r < 4; ++r)
#pragma unroll
            for (int i = 0; i < 3; ++i)
#pragma unroll
                for (int j = 0; j < 3; ++j) {
                    float v = base[r * SPD + i * HD + j];
                    s += v; sq += v * v;
                }
        float mu  = s * (1.f / 36.f);
        float var = (sq - 36.f * mu * mu) * (1.f / 35.f);
        zstT[n * 64 + cc] = make_float2(mu, rsqrtf(var + EPSF));
        return;
    }
    id -= N_TOT * 64;
    if (id >= CY * M_TOT) return;              // ---- C: y-stats
    int m  = id % M_TOT;                       // lanes = consecutive m -> coalesced
    int cc = id / M_TOT;
    int mi = m / M1, mj = m - mi * M1;
    const float* base = y + cc * (HY * HY) + mi * HY + mj;
    float s = 0.f, sq = 0.f;
#pragma unroll
    for (int i = 0; i < 3; ++i)
#pragma unroll
        for (int j = 0; j < 3; ++j) {
            float v = base[i * HY + j];
            s += v; sq += v * v;
        }
    float mu  = s * (1.f / 9.f);
    float var = (sq - 9.f * mu * mu) * (1.f / 8.f);
    ystT[m * 64 + cc] = make_float2(mu, sqrtf(var + EPSF));
}

// Per-(k,m,cc) affine coefficients: coef[k][m][cc] = (a, b) with a = y_sd/z_sd,
// b = y_mu - z_mu*a.  Also nsp[k][m] = spatial base offset of matched patch.
__global__ __launch_bounds__(256) void coef_kernel(const int* __restrict__ idx,
                                                   const float2* __restrict__ zstT,
                                                   const float2* __restrict__ ystT,
                                                   float2* __restrict__ coef,
                                                   int* __restrict__ nsp) {
    int gid = blockIdx.x * 256 + threadIdx.x;   // < KK*M_TOT*64
    int cc = gid & 63;
    int pair = gid >> 6;                        // k*M_TOT + m
    int k = pair / M_TOT, m = pair - k * M_TOT;
    int n = __builtin_amdgcn_readfirstlane(idx[m * KK + k]);
    float2 ys = ystT[m * 64 + cc];
    float2 zs = zstT[n * 64 + cc];
    float a = ys.y * zs.y;
    float b = fmaf(-zs.x, a, ys.x);
    coef[(size_t)pair * 64 + cc] = make_float2(a, b);
    if (cc == 0) nsp[pair] = (n / N1) * HD + (n - (n / N1) * N1);
}

// Main: block = 8 waves = 8 x-quads at one (k, quad-row y). Wave = (2x2 quad, one k),
// lanes = cc. Per patch: uniform nsp + coalesced coef + one b64 ydT4h load — depth-1.
// XCD-bijective swizzle gives each XCD a contiguous (k,y)-band for coef L2 reuse.
// Epilogue: LDS transpose -> every global store writes 4 FULL 64B lines.
__global__ __launch_bounds__(512) void agg_kernel(
    const uint2* __restrict__ ydT4h, const float2* __restrict__ coef,
    const int* __restrict__ nsp, float* __restrict__ out)
{
    __shared__ float lds[2 * CY * LPITCH];     // 8704 B

    int lane = threadIdx.x & 63;
    int wave = __builtin_amdgcn_readfirstlane(threadIdx.x >> 6);  // 0..7
    int bid  = blockIdx.x;                     // 0..3999
    int wg   = (bid & 7) * 500 + (bid >> 3);   // bijective XCD swizzle (4000 % 8 == 0)
    int k   = wg / 800;
    int rem = wg - k * 800;
    int y   = rem / 10;                        // quad row 0..79
    int xb  = rem - y * 10;                    // x block 0..9
    int x   = xb * 8 + wave;                   // quad col 0..79

    const float2* cfk  = coef + (size_t)k * M_TOT * 64;
    const int*    nspk = nsp + k * M_TOT;

    int mi_lo = max(0, y - 2), mi_hi = min(M1 - 1, y);
    int mj_lo = max(0, x - 2), mj_hi = min(M1 - 1, x);

    float acc[4] = {0.f, 0.f, 0.f, 0.f};
    int cnt;

    if (((mi_hi - mi_lo) == 2) && ((mj_hi - mj_lo) == 2)) {
        cnt = 9;
        int    sp_[9];
        float2 cf_[9];
#pragma unroll
        for (int p = 0; p < 9; ++p) {          // all independent, issued up front
            int m = (y - 2 + p / 3) * M1 + (x - 2 + p % 3);
            sp_[p] = nspk[m];
            cf_[p] = cfk[m * 64 + lane];
        }
        uint2 vq_[9];
#pragma unroll
        for (int p = 0; p < 9; ++p) {
            int sp = __builtin_amdgcn_readfirstlane(sp_[p])
                   + (2 - p / 3) * HD + (2 - p % 3);
            vq_[p] = ydT4h[sp * 64 + lane];
        }
#pragma unroll
        for (int p = 0; p < 9; ++p) {
            float a = cf_[p].x, b = cf_[p].y;
            unsigned lo = vq_[p].x, hi = vq_[p].y;
            float v0 = __uint_as_float(lo << 16);
            float v1 = __uint_as_float(lo & 0xffff0000u);
            float v2 = __uint_as_float(hi << 16);
            float v3 = __uint_as_float(hi & 0xffff0000u);
            acc[0] = fmaf(a, v0, acc[0] + b);
            acc[1] = fmaf(a, v1, acc[1] + b);
            acc[2] = fmaf(a, v2, acc[2] + b);
            acc[3] = fmaf(a, v3, acc[3] + b);
        }
    } else {
        cnt = (mi_hi - mi_lo + 1) * (mj_hi - mj_lo + 1);
        for (int mi = mi_lo; mi <= mi_hi; ++mi)
            for (int mj = mj_lo; mj <= mj_hi; ++mj) {
                int m = mi * M1 + mj;
                float2 cf = cfk[m * 64 + lane];
                int sp = __builtin_amdgcn_readfirstlane(nspk[m])
                       + (y - mi) * HD + (x - mj);
                uint2 vq = ydT4h[sp * 64 + lane];
                float a = cf.x, b = cf.y;
                float v0 = __uint_as_float(vq.x << 16);
                float v1 = __uint_as_float(vq.x & 0xffff0000u);
                float v2 = __uint_as_float(vq.y << 16);
                float v3 = __uint_as_float(vq.y & 0xffff0000u);
                acc[0] = fmaf(a, v0, acc[0] + b);
                acc[1] = fmaf(a, v1, acc[1] + b);
                acc[2] = fmaf(a, v2, acc[2] + b);
                acc[3] = fmaf(a, v3, acc[3] + b);
            }
    }

    float inv = 1.f / (float)cnt;

    // Stage: row = dy*64 + cc, col = wave*2 + dx. Lane stride 17 -> free 2-way.
#pragma unroll
    for (int dy = 0; dy < 2; ++dy) {
        int base = (dy * CY + lane) * LPITCH + wave * 2;
        lds[base]     = acc[dy * 2]     * inv;
        lds[base + 1] = acc[dy * 2 + 1] * inv;
    }

    __syncthreads();

    // Drain: 128 rows x 16 cols; each 16-lane group writes one FULL 64B line.
    int q  = lane >> 4;               // 0..3
    int xi = lane & 15;               // 0..15
    int X0 = xb * 16;
    int Y0 = 2 * y;
#pragma unroll
    for (int t = 0; t < 4; ++t) {
        int row = t * 32 + wave * 4 + q;       // 0..127
        int dy = row >> 6, cc = row & 63;
        float v = lds[row * LPITCH + xi];
        out[((size_t)(k * CY + cc) * HS + (Y0 + dy)) * HS + X0 + xi] = v;
    }
}

extern "C" void kernel_launch(void* const* d_in, const int* in_sizes, int n_in,
                              void* d_out, int out_size, void* d_ws, size_t ws_size,
                              hipStream_t stream) {
    const float* y   = (const float*)d_in[0];
    const float* yd  = (const float*)d_in[1];
    const int*   idx = (const int*)d_in[2];
    float* out = (float*)d_out;

    char* ws = (char*)d_ws;
    uint2*  ydT4h = (uint2*)ws;                                  //   819,200 B
    float2* zstT  = (float2*)(ws + 819200);                      //   739,328 B
    float2* ystT  = (float2*)(ws + 819200 + 739328);             // 3,115,008 B
    float2* coefb = (float2*)(ws + 819200 + 739328 + 3115008);   // 15,575,040 B
    int*    nspb  = (int*)(ws + 819200 + 739328 + 3115008 + 15575040); // 121,680 B

    int pre_total = SPD * 64 + N_TOT * 64 + CY * M_TOT;          // 584,192
    pre_kernel<<<(pre_total + 255) / 256, 256, 0, stream>>>(y, yd, ydT4h, zstT, ystT);
    coef_kernel<<<(KK * M_TOT * 64) / 256, 256, 0, stream>>>(idx, zstT, ystT, coefb, nspb);
    agg_kernel<<<KK * 800, 512, 0, stream>>>(ydT4h, coefb, nspb, out);
}

// Round 7
// 37.831 us; speedup vs baseline: 8.8859x; 1.1269x over previous
//
#include <hip/hip_runtime.h>

// Problem constants (SCALE=2, K=5, PATCH=3, STRIDE=1)
#define CY     64           // y channels
#define HY     80           // y spatial
#define HD     40           // yd spatial
#define SPD    (HD*HD)      // 1600
#define M1     78           // query patch grid dim
#define N1     38           // matched patch grid dim
#define M_TOT  (M1*M1)      // 6084
#define N_TOT  (N1*N1)      // 1444
#define KK     5
#define HS     160          // output spatial
#define EPSF   1e-5f
#define LP     33           // LDS row pitch (floats): b32 ops 2-way max (free)

// round-to-nearest-even f32->bf16, packed pair (a in low 16, b in high 16)
__device__ __forceinline__ unsigned bf16pk(float a, float b) {
    unsigned ua = __float_as_uint(a), ub = __float_as_uint(b);
    ua = (ua + 0x7fffu + ((ua >> 16) & 1u)) >> 16;
    ub = (ub + 0x7fffu + ((ub >> 16) & 1u)) >> 16;
    return ua | (ub << 16);
}

// Fused pre-pass, partitioned by flat thread id:
//  A: yd [256][1600] -> ydT4h[sp][cc] = 4 x bf16 over r (pixel-shuffle phases), 8B/lane
//  B: zstT[n][cc] = (mu, 1/sd) over 36 elems (f32)
//  C: ystT[m][cc] = (mu, sd) over 9 elems (f32)
__global__ __launch_bounds__(256) void pre_kernel(const float* __restrict__ y,
                                                  const float* __restrict__ yd,
                                                  uint2* __restrict__ ydT4h,
                                                  float2* __restrict__ zstT,
                                                  float2* __restrict__ ystT) {
    int id = blockIdx.x * 256 + threadIdx.x;
    if (id < SPD * 64) {                       // ---- A: transpose + bf16 pack
        int cc = id & 63, sp = id >> 6;
        float v0 = yd[(cc * 4 + 0) * SPD + sp];
        float v1 = yd[(cc * 4 + 1) * SPD + sp];
        float v2 = yd[(cc * 4 + 2) * SPD + sp];
        float v3 = yd[(cc * 4 + 3) * SPD + sp];
        ydT4h[sp * 64 + cc] = make_uint2(bf16pk(v0, v1), bf16pk(v2, v3));
        return;
    }
    id -= SPD * 64;
    if (id < N_TOT * 64) {                     // ---- B: z-stats
        int n  = id % N_TOT;                   // lanes = consecutive n -> coalesced
        int cc = id / N_TOT;
        int ni = n / N1, nj = n - ni * N1;
        const float* base = yd + (cc * 4) * SPD + ni * HD + nj;
        float s = 0.f, sq = 0.f;
#pragma unroll
        for (int r = 0; r < 4; ++r)
#pragma unroll
            for (int i = 0; i < 3; ++i)
#pragma unroll
                for (int j = 0; j < 3; ++j) {
                    float v = base[r * SPD + i * HD + j];
                    s += v; sq += v * v;
                }
        float mu  = s * (1.f / 36.f);
        float var = (sq - 36.f * mu * mu) * (1.f / 35.f);
        zstT[n * 64 + cc] = make_float2(mu, rsqrtf(var + EPSF));
        return;
    }
    id -= N_TOT * 64;
    if (id >= CY * M_TOT) return;              // ---- C: y-stats
    int m  = id % M_TOT;                       // lanes = consecutive m -> coalesced
    int cc = id / M_TOT;
    int mi = m / M1, mj = m - mi * M1;
    const float* base = y + cc * (HY * HY) + mi * HY + mj;
    float s = 0.f, sq = 0.f;
#pragma unroll
    for (int i = 0; i < 3; ++i)
#pragma unroll
        for (int j = 0; j < 3; ++j) {
            float v = base[i * HY + j];
            s += v; sq += v * v;
        }
    float mu  = s * (1.f / 9.f);
    float var = (sq - 9.f * mu * mu) * (1.f / 8.f);
    ystT[m * 64 + cc] = make_float2(mu, sqrtf(var + EPSF));
}

// Per-(k,m,cc) affine coefficients, bf16-packed: coef = pack(a, b), a = y_sd/z_sd,
// b = y_mu - z_mu*a.  nsp[k][m] = spatial base offset of matched patch.
__global__ __launch_bounds__(256) void coef_kernel(const int* __restrict__ idx,
                                                   const float2* __restrict__ zstT,
                                                   const float2* __restrict__ ystT,
                                                   unsigned* __restrict__ coef,
                                                   int* __restrict__ nsp) {
    int gid = blockIdx.x * 256 + threadIdx.x;   // < KK*M_TOT*64
    int cc = gid & 63;
    int pair = gid >> 6;                        // k*M_TOT + m
    int k = pair / M_TOT, m = pair - k * M_TOT;
    int n = __builtin_amdgcn_readfirstlane(idx[m * KK + k]);
    float2 ys = ystT[m * 64 + cc];
    float2 zs = zstT[n * 64 + cc];
    float a = ys.y * zs.y;
    float b = fmaf(-zs.x, a, ys.x);
    coef[(size_t)pair * 64 + cc] = bf16pk(a, b);
    if (cc == 0) nsp[pair] = (n / N1) * HD + (n - (n / N1) * N1);
}

__device__ __forceinline__ float bflo(unsigned u) { return __uint_as_float(u << 16); }
__device__ __forceinline__ float bfhi(unsigned u) { return __uint_as_float(u & 0xffff0000u); }

// Main: block = 8 waves; wave = TWO x-adjacent 2x2 quads (x0, x0+1) at one (k, quad-row y),
// lanes = cc. Patch union = 3 rows x 4 cols = 12 coef/nsp loads, 18 ydT4h loads, depth-1.
// acc = sum(a*v) per r-phase + sum(b) added once at the end.
// Epilogue: LDS transpose over the block's 32-pixel X span -> full-line-only stores.
__global__ __launch_bounds__(512) void agg_kernel(
    const uint2* __restrict__ ydT4h, const unsigned* __restrict__ coef,
    const int* __restrict__ nsp, float* __restrict__ out)
{
    __shared__ float lds[128 * LP];            // 16,896 B

    int lane = threadIdx.x & 63;
    int w    = __builtin_amdgcn_readfirstlane(threadIdx.x >> 6);  // 0..7
    int bid  = blockIdx.x;                     // 0..1999
    int wg   = (bid & 7) * 250 + (bid >> 3);   // bijective XCD swizzle (2000 % 8 == 0)
    int k    = wg / 400;
    int rem  = wg - k * 400;
    int y    = rem / 5;                        // quad row 0..79
    int xb2  = rem - y * 5;                    // x super-block 0..4 (32 X pixels)
    int x0   = xb2 * 16 + w * 2;               // quad A col; quad B = x0+1

    const unsigned* cfk  = coef + (size_t)k * M_TOT * 64;
    const int*      nspk = nsp + k * M_TOT;

    float acc[2][4];
    float bs[2] = {0.f, 0.f};
    float inv[2];
#pragma unroll
    for (int q = 0; q < 2; ++q)
#pragma unroll
        for (int r = 0; r < 4; ++r) acc[q][r] = 0.f;

    if (y >= 2 && y <= M1 - 1 && x0 >= 2 && x0 <= M1 - 2) {
        inv[0] = inv[1] = 1.f / 9.f;
        int      spv[12];
        unsigned cf[12];
#pragma unroll
        for (int p = 0; p < 12; ++p) {         // 12 independent loads, issued up front
            int m = (y - 2 + (p >> 2)) * M1 + (x0 - 2 + (p & 3));
            spv[p] = nspk[m];
            cf[p]  = cfk[m * 64 + lane];
        }
        int spb[12];
#pragma unroll
        for (int p = 0; p < 12; ++p)           // drain into SGPRs, free the VGPRs
            spb[p] = __builtin_amdgcn_readfirstlane(spv[p]);
#pragma unroll
        for (int r = 0; r < 3; ++r) {
            int b0 = spb[r * 4 + 0] + (2 - r) * HD;
            int b1 = spb[r * 4 + 1] + (2 - r) * HD;
            int b2 = spb[r * 4 + 2] + (2 - r) * HD;
            int b3 = spb[r * 4 + 3] + (2 - r) * HD;
            uint2 vA0 = ydT4h[(b0 + 2) * 64 + lane];   // quad A: cols 0..2, j = 2-c
            uint2 vA1 = ydT4h[(b1 + 1) * 64 + lane];
            uint2 vA2 = ydT4h[(b2 + 0) * 64 + lane];
            uint2 vB0 = ydT4h[(b1 + 2) * 64 + lane];   // quad B: cols 1..3, j = 3-c
            uint2 vB1 = ydT4h[(b2 + 1) * 64 + lane];
            uint2 vB2 = ydT4h[(b3 + 0) * 64 + lane];
            uint2 vA[3] = {vA0, vA1, vA2};
            uint2 vB[3] = {vB0, vB1, vB2};
#pragma unroll
            for (int c = 0; c < 3; ++c) {
                {
                    unsigned cv = cf[r * 4 + c];
                    float a = bfhi(cv) /*b-slot*/, dummy;
                    (void)dummy;
                    float aa = bflo(cv), bb = bfhi(cv);
                    bs[0] += bb;
                    acc[0][0] = fmaf(aa, bflo(vA[c].x), acc[0][0]);
                    acc[0][1] = fmaf(aa, bfhi(vA[c].x), acc[0][1]);
                    acc[0][2] = fmaf(aa, bflo(vA[c].y), acc[0][2]);
                    acc[0][3] = fmaf(aa, bfhi(vA[c].y), acc[0][3]);
                    (void)a;
                }
                {
                    unsigned cv = cf[r * 4 + c + 1];
                    float aa = bflo(cv), bb = bfhi(cv);
                    bs[1] += bb;
                    acc[1][0] = fmaf(aa, bflo(vB[c].x), acc[1][0]);
                    acc[1][1] = fmaf(aa, bfhi(vB[c].x), acc[1][1]);
                    acc[1][2] = fmaf(aa, bflo(vB[c].y), acc[1][2]);
                    acc[1][3] = fmaf(aa, bfhi(vB[c].y), acc[1][3]);
                }
            }
        }
    } else {
#pragma unroll
        for (int q = 0; q < 2; ++q) {
            int x = x0 + q;
            int milo = max(0, y - 2), mihi = min(M1 - 1, y);
            int mjlo = max(0, x - 2), mjhi = min(M1 - 1, x);
            inv[q] = 1.f / (float)((mihi - milo + 1) * (mjhi - mjlo + 1));
            for (int mi = milo; mi <= mihi; ++mi)
                for (int mj = mjlo; mj <= mjhi; ++mj) {
                    int m = mi * M1 + mj;
                    unsigned cv = cfk[m * 64 + lane];
                    int sp = __builtin_amdgcn_readfirstlane(nspk[m])
                           + (y - mi) * HD + (x - mj);
                    uint2 vq = ydT4h[sp * 64 + lane];
                    float aa = bflo(cv), bb = bfhi(cv);
                    bs[q] += bb;
                    acc[q][0] = fmaf(aa, bflo(vq.x), acc[q][0]);
                    acc[q][1] = fmaf(aa, bfhi(vq.x), acc[q][1]);
                    acc[q][2] = fmaf(aa, bflo(vq.y), acc[q][2]);
                    acc[q][3] = fmaf(aa, bfhi(vq.y), acc[q][3]);
                }
        }
    }

    // Stage: row = dy*64 + cc (128 rows), col = (w*2+q)*2 + dx (32 cols).
    // b32 writes at lane-stride LP=33 -> 2-way (free).
#pragma unroll
    for (int dy = 0; dy < 2; ++dy)
#pragma unroll
        for (int q = 0; q < 2; ++q) {
            int base = (dy * CY + lane) * LP + (w * 2 + q) * 2;
            lds[base]     = (acc[q][dy * 2]     + bs[q]) * inv[q];
            lds[base + 1] = (acc[q][dy * 2 + 1] + bs[q]) * inv[q];
        }

    __syncthreads();

    // Drain: each wave-store = 2 rows x 32 cols = 2 x 128B contiguous runs (full lines).
    int rsel = lane >> 5, c = lane & 31;
    int X0 = xb2 * 32, Y0 = 2 * y;
#pragma unroll
    for (int t = 0; t < 8; ++t) {
        int row = t * 16 + w * 2 + rsel;       // 0..127
        float v = lds[row * LP + c];
        int dy = row >> 6, cc = row & 63;
        out[((size_t)(k * CY + cc) * HS + (Y0 + dy)) * HS + X0 + c] = v;
    }
}

extern "C" void kernel_launch(void* const* d_in, const int* in_sizes, int n_in,
                              void* d_out, int out_size, void* d_ws, size_t ws_size,
                              hipStream_t stream) {
    const float* y   = (const float*)d_in[0];
    const float* yd  = (const float*)d_in[1];
    const int*   idx = (const int*)d_in[2];
    float* out = (float*)d_out;

    char* ws = (char*)d_ws;
    uint2*    ydT4h = (uint2*)ws;                                //   819,200 B
    float2*   zstT  = (float2*)(ws + 819200);                    //   739,328 B
    float2*   ystT  = (float2*)(ws + 819200 + 739328);           // 3,115,008 B
    unsigned* coefb = (unsigned*)(ws + 819200 + 739328 + 3115008);           // 7,787,520 B
    int*      nspb  = (int*)(ws + 819200 + 739328 + 3115008 + 7787520);      //   121,680 B

    int pre_total = SPD * 64 + N_TOT * 64 + CY * M_TOT;          // 584,192
    pre_kernel<<<(pre_total + 255) / 256, 256, 0, stream>>>(y, yd, ydT4h, zstT, ystT);
    coef_kernel<<<(KK * M_TOT * 64) / 256, 256, 0, stream>>>(idx, zstT, ystT, coefb, nspb);
    agg_kernel<<<KK * 400, 512, 0, stream>>>(ydT4h, coefb, nspb, out);
}